// Round 3
// baseline (159.726 us; speedup 1.0000x reference)
//
#include <hip/hip_runtime.h>

// LoopEmbeddingNetwork, round 3 (= round 2 + nontemporal-store compile fix).
// Insight: fc1/fc2/in_proj are per-NODE (N=100k), referenced 1.6M times (16x reuse).
// Precompute per-node qkv[48] once (node_qkv_kernel) into ws; the hot kernel
// (attn_tail_kernel, 1.6M threads) gathers qkv and does attention + tail only.
// q is pre-scaled by 1/sqrt(8)*log2(e) so softmax is exp2(s - max).
// All cross-token traffic via ds_swizzle with immediate patterns (8-lane groups).

typedef float f32x4 __attribute__((ext_vector_type(4)));

#define SWZ(x, pat) __uint_as_float((unsigned)__builtin_amdgcn_ds_swizzle((int)__float_as_uint(x), (pat)))

__global__ __launch_bounds__(512) void fuse_proj_kernel(
    const float* __restrict__ fc_w, const float* __restrict__ fc_b,
    const float* __restrict__ op_w, const float* __restrict__ op_b,
    float* __restrict__ w3, float* __restrict__ b3)
{
    int t = threadIdx.x;           // 512 threads: o = t>>4 (0..31), j = t&15
    int o = t >> 4, j = t & 15;
    float acc = 0.f;
#pragma unroll
    for (int e = 0; e < 16; ++e)
        acc = fmaf(fc_w[o * 16 + e], op_w[e * 16 + j], acc);
    w3[o * 16 + j] = acc;
    if (j == 0) {
        float bb = fc_b[o];
#pragma unroll
        for (int e = 0; e < 16; ++e)
            bb = fmaf(fc_w[o * 16 + e], op_b[e], bb);
        b3[o] = bb;
    }
}

// Per-node: gather nf -> fc1(relu) -> fc2 -> in_proj -> write qkv[48] (q pre-scaled)
__global__ __launch_bounds__(256) void node_qkv_kernel(
    const float* __restrict__ nf,
    const float* __restrict__ w1, const float* __restrict__ b1,
    const float* __restrict__ w2, const float* __restrict__ b2,
    const float* __restrict__ wip, const float* __restrict__ bip,
    float* __restrict__ qkvt, int N)
{
    int n = blockIdx.x * 256 + threadIdx.x;
    if (n >= N) return;
    const float2* nfp = reinterpret_cast<const float2*>(nf);
    float2 p0 = nfp[n * 3 + 0], p1 = nfp[n * 3 + 1], p2 = nfp[n * 3 + 2];
    float f[6] = {p0.x, p0.y, p1.x, p1.y, p2.x, p2.y};
    float h[32];
#pragma unroll
    for (int o = 0; o < 32; ++o) {
        float acc = b1[o];
#pragma unroll
        for (int i = 0; i < 6; ++i) acc = fmaf(f[i], w1[o * 6 + i], acc);
        h[o] = fmaxf(acc, 0.f);
    }
    float x[16];
#pragma unroll
    for (int e = 0; e < 16; ++e) {
        float acc = b2[e];
#pragma unroll
        for (int i = 0; i < 32; ++i) acc = fmaf(h[i], w2[e * 32 + i], acc);
        x[e] = acc;
    }
    float qkv[48];
#pragma unroll
    for (int c = 0; c < 48; ++c) {
        float acc = bip[c];
#pragma unroll
        for (int e = 0; e < 16; ++e) acc = fmaf(x[e], wip[c * 16 + e], acc);
        qkv[c] = acc;
    }
    const float cs = 0.35355339059327373f * 1.4426950408889634f; // 1/sqrt(8) * log2(e)
#pragma unroll
    for (int c = 0; c < 16; ++c) qkv[c] *= cs;
    f32x4* dst = reinterpret_cast<f32x4*>(qkvt) + (size_t)n * 12;
#pragma unroll
    for (int t = 0; t < 12; ++t) {
        f32x4 w; w.x = qkv[t * 4]; w.y = qkv[t * 4 + 1];
        w.z = qkv[t * 4 + 2]; w.w = qkv[t * 4 + 3];
        dst[t] = w;
    }
}

__global__ __launch_bounds__(256) void attn_tail_kernel(
    const int* __restrict__ s2l, const float* __restrict__ qkvt,
    const float* __restrict__ w3, const float* __restrict__ b3,
    const float* __restrict__ fow, const float* __restrict__ fob,
    float* __restrict__ out, int B)
{
    int tid = blockIdx.x * 256 + threadIdx.x;
    int b = tid >> 3;
    if (b >= B) return;
    int l = tid & 7;
    int idx = s2l[b * 8 + l];
    const f32x4* qp = reinterpret_cast<const f32x4*>(qkvt) + (size_t)idx * 12;

    f32x4 t0 = qp[0], t1 = qp[1], t2 = qp[2], t3 = qp[3];
    float q[16] = {t0.x, t0.y, t0.z, t0.w, t1.x, t1.y, t1.z, t1.w,
                   t2.x, t2.y, t2.z, t2.w, t3.x, t3.y, t3.z, t3.w};
    f32x4 u0 = qp[4], u1 = qp[5], u2 = qp[6], u3 = qp[7];
    float k[16] = {u0.x, u0.y, u0.z, u0.w, u1.x, u1.y, u1.z, u1.w,
                   u2.x, u2.y, u2.z, u2.w, u3.x, u3.y, u3.z, u3.w};

    // scores: broadcast k from lane m of each 8-lane group (ds_swizzle imm)
    float s0[8], s1[8];
#define SC_M(m) { float a0 = 0.f, a1 = 0.f; \
    _Pragma("unroll") for (int d = 0; d < 8; ++d) { \
        a0 = fmaf(q[d],     SWZ(k[d],     (((m) << 5) | 0x18)), a0); \
        a1 = fmaf(q[8 + d], SWZ(k[8 + d], (((m) << 5) | 0x18)), a1); } \
    s0[m] = a0; s1[m] = a1; }
    SC_M(0) SC_M(1) SC_M(2) SC_M(3) SC_M(4) SC_M(5) SC_M(6) SC_M(7)
#undef SC_M

    // softmax in exp2 domain (q pre-scaled)
    float mx0 = fmaxf(fmaxf(fmaxf(s0[0], s0[1]), fmaxf(s0[2], s0[3])),
                      fmaxf(fmaxf(s0[4], s0[5]), fmaxf(s0[6], s0[7])));
    float mx1 = fmaxf(fmaxf(fmaxf(s1[0], s1[1]), fmaxf(s1[2], s1[3])),
                      fmaxf(fmaxf(s1[4], s1[5]), fmaxf(s1[6], s1[7])));
    float e0[8], e1[8];
    float sum0 = 0.f, sum1 = 0.f;
#pragma unroll
    for (int m = 0; m < 8; ++m) {
        e0[m] = exp2f(s0[m] - mx0); sum0 += e0[m];
        e1[m] = exp2f(s1[m] - mx1); sum1 += e1[m];
    }
    float r0 = __builtin_amdgcn_rcpf(sum0);
    float r1 = __builtin_amdgcn_rcpf(sum1);
#pragma unroll
    for (int m = 0; m < 8; ++m) { e0[m] *= r0; e1[m] *= r1; }

    // v loaded only now (keeps peak VGPR down)
    f32x4 w0 = qp[8], w1v = qp[9], w2v = qp[10], w3v = qp[11];
    float v[16] = {w0.x, w0.y, w0.z, w0.w, w1v.x, w1v.y, w1v.z, w1v.w,
                   w2v.x, w2v.y, w2v.z, w2v.w, w3v.x, w3v.y, w3v.z, w3v.w};
    float ctx[16];
#pragma unroll
    for (int c = 0; c < 16; ++c) ctx[c] = 0.f;
#define CTX_M(m) { \
    _Pragma("unroll") for (int c = 0; c < 8; ++c) \
        ctx[c]     = fmaf(e0[m], SWZ(v[c],     (((m) << 5) | 0x18)), ctx[c]); \
    _Pragma("unroll") for (int c = 0; c < 8; ++c) \
        ctx[8 + c] = fmaf(e1[m], SWZ(v[8 + c], (((m) << 5) | 0x18)), ctx[8 + c]); }
    CTX_M(0) CTX_M(1) CTX_M(2) CTX_M(3) CTX_M(4) CTX_M(5) CTX_M(6) CTX_M(7)
#undef CTX_M

    // fused out_proj+fc: 16 -> 32, relu
    float y[32];
#pragma unroll
    for (int o = 0; o < 32; ++o) {
        float acc = b3[o];
#pragma unroll
        for (int j = 0; j < 16; ++j) acc = fmaf(ctx[j], w3[o * 16 + j], acc);
        y[o] = fmaxf(acc, 0.f);
    }

    // mean over 8 tokens: swizzle-xor butterfly
#pragma unroll
    for (int o = 0; o < 32; ++o) {
        y[o] += SWZ(y[o], 0x041F);
        y[o] += SWZ(y[o], 0x081F);
        y[o] += SWZ(y[o], 0x101F);
    }

    // fco: each of the 8 lanes computes 4 outputs (vector float4 weight loads, L1-hot)
    const f32x4* fr = reinterpret_cast<const f32x4*>(fow);
    float o4[4];
#pragma unroll
    for (int j = 0; j < 4; ++j) {
        int oo = l * 4 + j;
        float acc = 0.f;
#pragma unroll
        for (int i8 = 0; i8 < 8; ++i8) {
            f32x4 w = fr[oo * 8 + i8];
            acc = fmaf(w.x, y[i8 * 4 + 0], acc);
            acc = fmaf(w.y, y[i8 * 4 + 1], acc);
            acc = fmaf(w.z, y[i8 * 4 + 2], acc);
            acc = fmaf(w.w, y[i8 * 4 + 3], acc);
        }
        o4[j] = fmaf(acc, 0.125f, fob[oo]);  // fold mean's 1/8
    }
    f32x4 res; res.x = o4[0]; res.y = o4[1]; res.z = o4[2]; res.w = o4[3];
    __builtin_nontemporal_store(res, reinterpret_cast<f32x4*>(out) + (b * 8 + l));
}

// ---------------- fallback: round-1 monolithic kernel (if ws too small) ----------------
__global__ __launch_bounds__(256) void loop_embed_kernel(
    const float* __restrict__ nf, const int* __restrict__ s2l,
    const float* __restrict__ w1, const float* __restrict__ b1,
    const float* __restrict__ w2, const float* __restrict__ b2,
    const float* __restrict__ wip, const float* __restrict__ bip,
    const float* __restrict__ w3, const float* __restrict__ b3,
    const float* __restrict__ fow, const float* __restrict__ fob,
    float* __restrict__ out, int B)
{
    int tid = blockIdx.x * 256 + threadIdx.x;
    int b = tid >> 3;
    if (b >= B) return;
    int l = tid & 7;
    int idx = s2l[b * 8 + l];
    const float2* nfp = reinterpret_cast<const float2*>(nf);
    float2 p0 = nfp[idx * 3 + 0], p1 = nfp[idx * 3 + 1], p2 = nfp[idx * 3 + 2];
    float f[6] = {p0.x, p0.y, p1.x, p1.y, p2.x, p2.y};
    float h[32];
#pragma unroll
    for (int o = 0; o < 32; ++o) {
        float acc = b1[o];
#pragma unroll
        for (int i = 0; i < 6; ++i) acc = fmaf(f[i], w1[o * 6 + i], acc);
        h[o] = fmaxf(acc, 0.f);
    }
    float x[16];
#pragma unroll
    for (int e = 0; e < 16; ++e) {
        float acc = b2[e];
#pragma unroll
        for (int i = 0; i < 32; ++i) acc = fmaf(h[i], w2[e * 32 + i], acc);
        x[e] = acc;
    }
    float q[16], k[16], v[16];
#pragma unroll
    for (int c = 0; c < 16; ++c) {
        float aq = bip[c], ak = bip[16 + c], av = bip[32 + c];
#pragma unroll
        for (int e = 0; e < 16; ++e) {
            aq = fmaf(x[e], wip[c * 16 + e], aq);
            ak = fmaf(x[e], wip[(16 + c) * 16 + e], ak);
            av = fmaf(x[e], wip[(32 + c) * 16 + e], av);
        }
        q[c] = aq; k[c] = ak; v[c] = av;
    }
    int lane = threadIdx.x & 63;
    int gb = lane & 56;
    float s0[8], s1[8];
#pragma unroll
    for (int m = 0; m < 8; ++m) {
        float a0 = 0.f, a1 = 0.f;
#pragma unroll
        for (int d = 0; d < 8; ++d) {
            a0 = fmaf(q[d], __shfl(k[d], gb + m, 64), a0);
            a1 = fmaf(q[8 + d], __shfl(k[8 + d], gb + m, 64), a1);
        }
        s0[m] = a0; s1[m] = a1;
    }
    const float sc = 0.35355339059327373f;
    float mx0 = s0[0], mx1 = s1[0];
#pragma unroll
    for (int m = 1; m < 8; ++m) { mx0 = fmaxf(mx0, s0[m]); mx1 = fmaxf(mx1, s1[m]); }
    float e0[8], e1[8];
    float sum0 = 0.f, sum1 = 0.f;
#pragma unroll
    for (int m = 0; m < 8; ++m) {
        e0[m] = __expf((s0[m] - mx0) * sc); sum0 += e0[m];
        e1[m] = __expf((s1[m] - mx1) * sc); sum1 += e1[m];
    }
    float r0 = 1.0f / sum0, r1 = 1.0f / sum1;
    float ctx[16];
#pragma unroll
    for (int c = 0; c < 16; ++c) ctx[c] = 0.f;
#pragma unroll
    for (int m = 0; m < 8; ++m) {
#pragma unroll
        for (int c = 0; c < 8; ++c)
            ctx[c] = fmaf(e0[m], __shfl(v[c], gb + m, 64), ctx[c]);
#pragma unroll
        for (int c = 8; c < 16; ++c)
            ctx[c] = fmaf(e1[m], __shfl(v[c], gb + m, 64), ctx[c]);
    }
#pragma unroll
    for (int c = 0; c < 8; ++c)  ctx[c] *= r0;
#pragma unroll
    for (int c = 8; c < 16; ++c) ctx[c] *= r1;
    float y[32];
#pragma unroll
    for (int o = 0; o < 32; ++o) {
        float acc = b3[o];
#pragma unroll
        for (int j = 0; j < 16; ++j) acc = fmaf(ctx[j], w3[o * 16 + j], acc);
        y[o] = fmaxf(acc, 0.f);
    }
#pragma unroll
    for (int o = 0; o < 32; ++o) {
        y[o] += __shfl_xor(y[o], 1, 64);
        y[o] += __shfl_xor(y[o], 2, 64);
        y[o] += __shfl_xor(y[o], 4, 64);
    }
    float o4[4];
#pragma unroll
    for (int j = 0; j < 4; ++j) {
        int oo = l * 4 + j;
        float acc = 0.f;
#pragma unroll
        for (int i = 0; i < 32; ++i) acc = fmaf(y[i], fow[oo * 32 + i], acc);
        o4[j] = fmaf(acc, 0.125f, fob[oo]);
    }
    reinterpret_cast<float4*>(out)[b * 8 + l] = make_float4(o4[0], o4[1], o4[2], o4[3]);
}

extern "C" void kernel_launch(void* const* d_in, const int* in_sizes, int n_in,
                              void* d_out, int out_size, void* d_ws, size_t ws_size,
                              hipStream_t stream) {
    const float* nf  = (const float*)d_in[0];
    const int*   s2l = (const int*)d_in[1];
    const float* w1  = (const float*)d_in[2];
    const float* b1  = (const float*)d_in[3];
    const float* w2  = (const float*)d_in[4];
    const float* b2  = (const float*)d_in[5];
    const float* wip = (const float*)d_in[6];
    const float* bip = (const float*)d_in[7];
    const float* opw = (const float*)d_in[8];
    const float* opb = (const float*)d_in[9];
    const float* fcw = (const float*)d_in[10];
    const float* fcb = (const float*)d_in[11];
    const float* fow = (const float*)d_in[12];
    const float* fob = (const float*)d_in[13];
    float* out = (float*)d_out;

    int N = in_sizes[0] / 6;
    int B = in_sizes[1] / 8;

    float* w3 = (float*)d_ws;          // 512 floats
    float* b3 = w3 + 512;              // 32 floats
    float* qkvt = w3 + 544;            // N*48 floats, 16B-aligned (544*4 = 2176)

    size_t need = (size_t)(544 + (size_t)N * 48) * 4;

    fuse_proj_kernel<<<1, 512, 0, stream>>>(fcw, fcb, opw, opb, w3, b3);

    int total = B * 8;
    int blocks = (total + 255) / 256;

    if (ws_size >= need) {
        node_qkv_kernel<<<(N + 255) / 256, 256, 0, stream>>>(
            nf, w1, b1, w2, b2, wip, bip, qkvt, N);
        attn_tail_kernel<<<blocks, 256, 0, stream>>>(
            s2l, qkvt, w3, b3, fow, fob, out, B);
    } else {
        loop_embed_kernel<<<blocks, 256, 0, stream>>>(
            nf, s2l, w1, b1, w2, b2, wip, bip, w3, b3, fow, fob, out, B);
    }
    (void)n_in; (void)out_size;
}

// Round 5
// 127.706 us; speedup vs baseline: 1.2507x; 1.2507x over previous
//
#include <hip/hip_runtime.h>

// LoopEmbeddingNetwork, round 5 (= round 4 + __fp16 vector type fix).
// R3 post-mortem: 352 ds_swizzle/thread saturate the per-CU LDS pipe (~83us).
// All cross-lane exchange via VALU DPP (quad_perm / row_half_mirror = XOR 0..7
// within 8-lane groups); tail FMAs halved with fp16-packed weights + fdot2.
// q/k/v stay fp32 (softmax path is precision-critical).

typedef float f32x4 __attribute__((ext_vector_type(4)));
typedef __fp16 h2 __attribute__((ext_vector_type(2)));   // matches cvt_pkrtz return

// DPP ctrl: quad_perm[1,0,3,2]=0xB1 (xor1), [2,3,0,1]=0x4E (xor2),
// [3,2,1,0]=0x1B (xor3), row_half_mirror=0x141 (xor7 within 8 lanes).
#define DPPF(x, ctrl) __uint_as_float((unsigned)__builtin_amdgcn_update_dpp( \
    (int)__float_as_uint(x), (int)__float_as_uint(x), (ctrl), 0xF, 0xF, false))

static __device__ __forceinline__ unsigned h2u(h2 v) { return __builtin_bit_cast(unsigned, v); }
static __device__ __forceinline__ h2 u2h(unsigned v) { return __builtin_bit_cast(h2, v); }
#define DPPH2(x, ctrl) u2h((unsigned)__builtin_amdgcn_update_dpp( \
    (int)h2u(x), (int)h2u(x), (ctrl), 0xF, 0xF, false))

#if defined(__has_builtin) && __has_builtin(__builtin_amdgcn_fdot2)
#define FDOT2(a, b, c) __builtin_amdgcn_fdot2((a), (b), (c), false)
#else
#define FDOT2(a, b, c) fmaf((float)(a).x, (float)(b).x, fmaf((float)(a).y, (float)(b).y, (c)))
#endif

// fuse out_proj+fc -> W3 (f32 + fp16-packed), pack fco weights to fp16.
__global__ __launch_bounds__(512) void fuse_proj_kernel(
    const float* __restrict__ fc_w, const float* __restrict__ fc_b,
    const float* __restrict__ op_w, const float* __restrict__ op_b,
    const float* __restrict__ fow,
    h2* __restrict__ w3h, float* __restrict__ w3f, float* __restrict__ b3,
    h2* __restrict__ fowh)
{
    __shared__ float lw[512];
    int t = threadIdx.x;           // 512 threads: o = t>>4 (0..31), j = t&15
    int o = t >> 4, j = t & 15;
    float acc = 0.f;
#pragma unroll
    for (int e = 0; e < 16; ++e)
        acc = fmaf(fc_w[o * 16 + e], op_w[e * 16 + j], acc);
    lw[t] = acc;
    if (j == 0) {
        float bb = fc_b[o];
#pragma unroll
        for (int e = 0; e < 16; ++e)
            bb = fmaf(fc_w[o * 16 + e], op_b[e], bb);
        b3[o] = bb;
    }
    // fco weight pack: 1024 floats -> 512 h2
    fowh[t] = __builtin_amdgcn_cvt_pkrtz(fow[2 * t], fow[2 * t + 1]);
    __syncthreads();
    if (t < 256) {
        float a = lw[2 * t], bv = lw[2 * t + 1];
        w3h[t] = __builtin_amdgcn_cvt_pkrtz(a, bv);
        w3f[2 * t] = a; w3f[2 * t + 1] = bv;
    }
}

// Per-node: gather nf -> fc1(relu) -> fc2 -> in_proj -> write qkv[48] (q pre-scaled)
__global__ __launch_bounds__(256) void node_qkv_kernel(
    const float* __restrict__ nf,
    const float* __restrict__ w1, const float* __restrict__ b1,
    const float* __restrict__ w2, const float* __restrict__ b2,
    const float* __restrict__ wip, const float* __restrict__ bip,
    float* __restrict__ qkvt, int N)
{
    int n = blockIdx.x * 256 + threadIdx.x;
    if (n >= N) return;
    const float2* nfp = reinterpret_cast<const float2*>(nf);
    float2 p0 = nfp[n * 3 + 0], p1 = nfp[n * 3 + 1], p2 = nfp[n * 3 + 2];
    float f[6] = {p0.x, p0.y, p1.x, p1.y, p2.x, p2.y};
    float h[32];
#pragma unroll
    for (int o = 0; o < 32; ++o) {
        float acc = b1[o];
#pragma unroll
        for (int i = 0; i < 6; ++i) acc = fmaf(f[i], w1[o * 6 + i], acc);
        h[o] = fmaxf(acc, 0.f);
    }
    float x[16];
#pragma unroll
    for (int e = 0; e < 16; ++e) {
        float acc = b2[e];
#pragma unroll
        for (int i = 0; i < 32; ++i) acc = fmaf(h[i], w2[e * 32 + i], acc);
        x[e] = acc;
    }
    float qkv[48];
#pragma unroll
    for (int c = 0; c < 48; ++c) {
        float acc = bip[c];
#pragma unroll
        for (int e = 0; e < 16; ++e) acc = fmaf(x[e], wip[c * 16 + e], acc);
        qkv[c] = acc;
    }
    const float cs = 0.35355339059327373f * 1.4426950408889634f; // 1/sqrt(8) * log2(e)
#pragma unroll
    for (int c = 0; c < 16; ++c) qkv[c] *= cs;
    f32x4* dst = reinterpret_cast<f32x4*>(qkvt) + (size_t)n * 12;
#pragma unroll
    for (int t = 0; t < 12; ++t) {
        f32x4 w; w.x = qkv[t * 4]; w.y = qkv[t * 4 + 1];
        w.z = qkv[t * 4 + 2]; w.w = qkv[t * 4 + 3];
        dst[t] = w;
    }
}

__global__ __launch_bounds__(256) void attn_tail_kernel(
    const int* __restrict__ s2l, const float* __restrict__ qkvt,
    const h2* __restrict__ w3h, const float* __restrict__ b3,
    const h2* __restrict__ fowh, const float* __restrict__ fob,
    float* __restrict__ out, int B)
{
    int tid = blockIdx.x * 256 + threadIdx.x;
    int b = tid >> 3;
    if (b >= B) return;
    int l = tid & 7;
    int idx = s2l[b * 8 + l];
    const f32x4* qp = reinterpret_cast<const f32x4*>(qkvt) + (size_t)idx * 12;

    f32x4 t0 = qp[0], t1 = qp[1], t2 = qp[2], t3 = qp[3];
    float q[16] = {t0.x, t0.y, t0.z, t0.w, t1.x, t1.y, t1.z, t1.w,
                   t2.x, t2.y, t2.z, t2.w, t3.x, t3.y, t3.z, t3.w};
    f32x4 u0 = qp[4], u1 = qp[5], u2 = qp[6], u3 = qp[7];
    float k[16] = {u0.x, u0.y, u0.z, u0.w, u1.x, u1.y, u1.z, u1.w,
                   u2.x, u2.y, u2.z, u2.w, u3.x, u3.y, u3.z, u3.w};

    // half-mirrored copy (partner l^7); slots 4..6 are quad_perms of it
    float k7[16];
#pragma unroll
    for (int d = 0; d < 16; ++d) k7[d] = DPPF(k[d], 0x141);

    // scores: slot o holds q(self) . k(lane^o)
    float s0[8], s1[8];
#define SC_ID(slot, KS) { float a0 = 0.f, a1 = 0.f; \
    _Pragma("unroll") for (int d = 0; d < 8; ++d) { \
        a0 = fmaf(q[d], KS[d], a0); a1 = fmaf(q[8 + d], KS[8 + d], a1); } \
    s0[slot] = a0; s1[slot] = a1; }
#define SC_DPP(slot, KS, CTRL) { float a0 = 0.f, a1 = 0.f; \
    _Pragma("unroll") for (int d = 0; d < 8; ++d) { \
        a0 = fmaf(q[d], DPPF(KS[d], CTRL), a0); \
        a1 = fmaf(q[8 + d], DPPF(KS[8 + d], CTRL), a1); } \
    s0[slot] = a0; s1[slot] = a1; }
    SC_ID(0, k)
    SC_DPP(1, k, 0xB1)
    SC_DPP(2, k, 0x4E)
    SC_DPP(3, k, 0x1B)
    SC_DPP(4, k7, 0x1B)
    SC_DPP(5, k7, 0x4E)
    SC_DPP(6, k7, 0xB1)
    SC_ID(7, k7)
#undef SC_ID
#undef SC_DPP

    // softmax in exp2 domain (q pre-scaled)
    float mx0 = fmaxf(fmaxf(fmaxf(s0[0], s0[1]), fmaxf(s0[2], s0[3])),
                      fmaxf(fmaxf(s0[4], s0[5]), fmaxf(s0[6], s0[7])));
    float mx1 = fmaxf(fmaxf(fmaxf(s1[0], s1[1]), fmaxf(s1[2], s1[3])),
                      fmaxf(fmaxf(s1[4], s1[5]), fmaxf(s1[6], s1[7])));
    float e0[8], e1[8];
    float sum0 = 0.f, sum1 = 0.f;
#pragma unroll
    for (int m = 0; m < 8; ++m) {
        e0[m] = exp2f(s0[m] - mx0); sum0 += e0[m];
        e1[m] = exp2f(s1[m] - mx1); sum1 += e1[m];
    }
    float r0 = __builtin_amdgcn_rcpf(sum0);
    float r1 = __builtin_amdgcn_rcpf(sum1);
#pragma unroll
    for (int m = 0; m < 8; ++m) { e0[m] *= r0; e1[m] *= r1; }

    // v loaded only now; same XOR-slot decomposition
    f32x4 w0 = qp[8], w1v = qp[9], w2v = qp[10], w3v = qp[11];
    float v[16] = {w0.x, w0.y, w0.z, w0.w, w1v.x, w1v.y, w1v.z, w1v.w,
                   w2v.x, w2v.y, w2v.z, w2v.w, w3v.x, w3v.y, w3v.z, w3v.w};
    float v7[16];
#pragma unroll
    for (int d = 0; d < 16; ++d) v7[d] = DPPF(v[d], 0x141);

    float ctx[16];
#pragma unroll
    for (int c = 0; c < 16; ++c) ctx[c] = 0.f;
#define CTX_ID(slot, VS) { \
    _Pragma("unroll") for (int c = 0; c < 8; ++c) { \
        ctx[c]     = fmaf(e0[slot], VS[c],     ctx[c]); \
        ctx[8 + c] = fmaf(e1[slot], VS[8 + c], ctx[8 + c]); } }
#define CTX_DPP(slot, VS, CTRL) { \
    _Pragma("unroll") for (int c = 0; c < 8; ++c) { \
        ctx[c]     = fmaf(e0[slot], DPPF(VS[c], CTRL),     ctx[c]); \
        ctx[8 + c] = fmaf(e1[slot], DPPF(VS[8 + c], CTRL), ctx[8 + c]); } }
    CTX_ID(0, v)
    CTX_DPP(1, v, 0xB1)
    CTX_DPP(2, v, 0x4E)
    CTX_DPP(3, v, 0x1B)
    CTX_DPP(4, v7, 0x1B)
    CTX_DPP(5, v7, 0x4E)
    CTX_DPP(6, v7, 0xB1)
    CTX_ID(7, v7)
#undef CTX_ID
#undef CTX_DPP

    // pack ctx -> fp16 pairs; fused out_proj+fc (16->32, relu) via fdot2
    h2 ch[8];
#pragma unroll
    for (int i = 0; i < 8; ++i)
        ch[i] = __builtin_amdgcn_cvt_pkrtz(ctx[2 * i], ctx[2 * i + 1]);
    h2 yh[16];
#pragma unroll
    for (int i = 0; i < 16; ++i) {
        float ya = b3[2 * i], yb = b3[2 * i + 1];
#pragma unroll
        for (int jj = 0; jj < 8; ++jj) {
            ya = FDOT2(ch[jj], w3h[(2 * i) * 8 + jj], ya);
            yb = FDOT2(ch[jj], w3h[(2 * i + 1) * 8 + jj], yb);
        }
        yh[i] = __builtin_amdgcn_cvt_pkrtz(fmaxf(ya, 0.f), fmaxf(yb, 0.f));
    }

    // mean over 8 tokens: DPP butterfly on packed fp16 (xor1, xor2, xor4)
#pragma unroll
    for (int i = 0; i < 16; ++i) {
        yh[i] = yh[i] + DPPH2(yh[i], 0xB1);
        yh[i] = yh[i] + DPPH2(yh[i], 0x4E);
        h2 t = DPPH2(yh[i], 0x141);   // xor7
        t = DPPH2(t, 0x1B);           // xor3 of that = xor4
        yh[i] = yh[i] + t;
    }

    // fco: each of the 8 lanes computes 4 outputs via fdot2 on packed sums
    float o4[4];
#pragma unroll
    for (int j = 0; j < 4; ++j) {
        int oo = l * 4 + j;
        float acc = 0.f;
#pragma unroll
        for (int i = 0; i < 16; ++i)
            acc = FDOT2(yh[i], fowh[oo * 16 + i], acc);
        o4[j] = fmaf(acc, 0.125f, fob[oo]);  // fold mean's 1/8
    }
    f32x4 res; res.x = o4[0]; res.y = o4[1]; res.z = o4[2]; res.w = o4[3];
    __builtin_nontemporal_store(res, reinterpret_cast<f32x4*>(out) + (b * 8 + l));
}

// ---------------- fallback: round-1 monolithic kernel (if ws too small) ----------------
__global__ __launch_bounds__(256) void loop_embed_kernel(
    const float* __restrict__ nf, const int* __restrict__ s2l,
    const float* __restrict__ w1, const float* __restrict__ b1,
    const float* __restrict__ w2, const float* __restrict__ b2,
    const float* __restrict__ wip, const float* __restrict__ bip,
    const float* __restrict__ w3, const float* __restrict__ b3,
    const float* __restrict__ fow, const float* __restrict__ fob,
    float* __restrict__ out, int B)
{
    int tid = blockIdx.x * 256 + threadIdx.x;
    int b = tid >> 3;
    if (b >= B) return;
    int l = tid & 7;
    int idx = s2l[b * 8 + l];
    const float2* nfp = reinterpret_cast<const float2*>(nf);
    float2 p0 = nfp[idx * 3 + 0], p1 = nfp[idx * 3 + 1], p2 = nfp[idx * 3 + 2];
    float f[6] = {p0.x, p0.y, p1.x, p1.y, p2.x, p2.y};
    float h[32];
#pragma unroll
    for (int o = 0; o < 32; ++o) {
        float acc = b1[o];
#pragma unroll
        for (int i = 0; i < 6; ++i) acc = fmaf(f[i], w1[o * 6 + i], acc);
        h[o] = fmaxf(acc, 0.f);
    }
    float x[16];
#pragma unroll
    for (int e = 0; e < 16; ++e) {
        float acc = b2[e];
#pragma unroll
        for (int i = 0; i < 32; ++i) acc = fmaf(h[i], w2[e * 32 + i], acc);
        x[e] = acc;
    }
    float q[16], k[16], v[16];
#pragma unroll
    for (int c = 0; c < 16; ++c) {
        float aq = bip[c], ak = bip[16 + c], av = bip[32 + c];
#pragma unroll
        for (int e = 0; e < 16; ++e) {
            aq = fmaf(x[e], wip[c * 16 + e], aq);
            ak = fmaf(x[e], wip[(16 + c) * 16 + e], ak);
            av = fmaf(x[e], wip[(32 + c) * 16 + e], av);
        }
        q[c] = aq; k[c] = ak; v[c] = av;
    }
    int lane = threadIdx.x & 63;
    int gb = lane & 56;
    float s0[8], s1[8];
#pragma unroll
    for (int m = 0; m < 8; ++m) {
        float a0 = 0.f, a1 = 0.f;
#pragma unroll
        for (int d = 0; d < 8; ++d) {
            a0 = fmaf(q[d], __shfl(k[d], gb + m, 64), a0);
            a1 = fmaf(q[8 + d], __shfl(k[8 + d], gb + m, 64), a1);
        }
        s0[m] = a0; s1[m] = a1;
    }
    const float sc = 0.35355339059327373f;
    float mx0 = s0[0], mx1 = s1[0];
#pragma unroll
    for (int m = 1; m < 8; ++m) { mx0 = fmaxf(mx0, s0[m]); mx1 = fmaxf(mx1, s1[m]); }
    float e0[8], e1[8];
    float sum0 = 0.f, sum1 = 0.f;
#pragma unroll
    for (int m = 0; m < 8; ++m) {
        e0[m] = __expf((s0[m] - mx0) * sc); sum0 += e0[m];
        e1[m] = __expf((s1[m] - mx1) * sc); sum1 += e1[m];
    }
    float r0 = 1.0f / sum0, r1 = 1.0f / sum1;
    float ctx[16];
#pragma unroll
    for (int c = 0; c < 16; ++c) ctx[c] = 0.f;
#pragma unroll
    for (int m = 0; m < 8; ++m) {
#pragma unroll
        for (int c = 0; c < 8; ++c)
            ctx[c] = fmaf(e0[m], __shfl(v[c], gb + m, 64), ctx[c]);
#pragma unroll
        for (int c = 8; c < 16; ++c)
            ctx[c] = fmaf(e1[m], __shfl(v[c], gb + m, 64), ctx[c]);
    }
#pragma unroll
    for (int c = 0; c < 8; ++c)  ctx[c] *= r0;
#pragma unroll
    for (int c = 8; c < 16; ++c) ctx[c] *= r1;
    float y[32];
#pragma unroll
    for (int o = 0; o < 32; ++o) {
        float acc = b3[o];
#pragma unroll
        for (int j = 0; j < 16; ++j) acc = fmaf(ctx[j], w3[o * 16 + j], acc);
        y[o] = fmaxf(acc, 0.f);
    }
#pragma unroll
    for (int o = 0; o < 32; ++o) {
        y[o] += __shfl_xor(y[o], 1, 64);
        y[o] += __shfl_xor(y[o], 2, 64);
        y[o] += __shfl_xor(y[o], 4, 64);
    }
    float o4[4];
#pragma unroll
    for (int j = 0; j < 4; ++j) {
        int oo = l * 4 + j;
        float acc = 0.f;
#pragma unroll
        for (int i = 0; i < 32; ++i) acc = fmaf(y[i], fow[oo * 32 + i], acc);
        o4[j] = fmaf(acc, 0.125f, fob[oo]);
    }
    reinterpret_cast<float4*>(out)[b * 8 + l] = make_float4(o4[0], o4[1], o4[2], o4[3]);
}

extern "C" void kernel_launch(void* const* d_in, const int* in_sizes, int n_in,
                              void* d_out, int out_size, void* d_ws, size_t ws_size,
                              hipStream_t stream) {
    const float* nf  = (const float*)d_in[0];
    const int*   s2l = (const int*)d_in[1];
    const float* w1  = (const float*)d_in[2];
    const float* b1  = (const float*)d_in[3];
    const float* w2  = (const float*)d_in[4];
    const float* b2  = (const float*)d_in[5];
    const float* wip = (const float*)d_in[6];
    const float* bip = (const float*)d_in[7];
    const float* opw = (const float*)d_in[8];
    const float* opb = (const float*)d_in[9];
    const float* fcw = (const float*)d_in[10];
    const float* fcb = (const float*)d_in[11];
    const float* fow = (const float*)d_in[12];
    const float* fob = (const float*)d_in[13];
    float* out = (float*)d_out;

    int N = in_sizes[0] / 6;
    int B = in_sizes[1] / 8;

    // ws layout (dwords): [0,256) w3h  [256,768) fowh  [768,800) b3
    //                     [800,1312) w3f (fallback)  [1312,...) qkv table
    unsigned* wsd = (unsigned*)d_ws;
    h2*    w3h  = (h2*)(wsd);
    h2*    fowh = (h2*)(wsd + 256);
    float* b3   = (float*)(wsd + 768);
    float* w3f  = (float*)(wsd + 800);
    float* qkvt = (float*)(wsd + 1312);

    size_t need = (size_t)(1312 + (size_t)N * 48) * 4;

    fuse_proj_kernel<<<1, 512, 0, stream>>>(fcw, fcb, opw, opb, fow,
                                            w3h, w3f, b3, fowh);

    int total = B * 8;
    int blocks = (total + 255) / 256;

    if (ws_size >= need) {
        node_qkv_kernel<<<(N + 255) / 256, 256, 0, stream>>>(
            nf, w1, b1, w2, b2, wip, bip, qkvt, N);
        attn_tail_kernel<<<blocks, 256, 0, stream>>>(
            s2l, qkvt, w3h, b3, fowh, fob, out, B);
    } else {
        loop_embed_kernel<<<blocks, 256, 0, stream>>>(
            nf, s2l, w1, b1, w2, b2, wip, bip, w3f, b3, fow, fob, out, B);
    }
    (void)n_in; (void)out_size;
}

// Round 6
// 97.723 us; speedup vs baseline: 1.6345x; 1.3068x over previous
//
#include <hip/hip_runtime.h>

// LoopEmbeddingNetwork, round 6.
// R5 post-mortem: duration == L2-miss bytes / ~2.45 TB/s -> gather-traffic-bound.
// This round stores the per-node qkv table in fp16 (96 B/node, was 192), and
// does attention in packed-fp16: fdot2 scores (f32 acc), v_fma_mix ctx (f32 acc).
// Cross-lane exchange stays on VALU DPP, now on packed h2 regs (half the movs).

typedef float f32x4 __attribute__((ext_vector_type(4)));
typedef __fp16 h2 __attribute__((ext_vector_type(2)));   // matches cvt_pkrtz return

// DPP ctrl: quad_perm[1,0,3,2]=0xB1 (xor1), [2,3,0,1]=0x4E (xor2),
// [3,2,1,0]=0x1B (xor3), row_half_mirror=0x141 (xor7 within 8 lanes).
static __device__ __forceinline__ unsigned h2u(h2 v) { return __builtin_bit_cast(unsigned, v); }
static __device__ __forceinline__ h2 u2h(unsigned v) { return __builtin_bit_cast(h2, v); }
static __device__ __forceinline__ h2 f2h(float v) { return __builtin_bit_cast(h2, v); }
static __device__ __forceinline__ float h2f(h2 v) { return __builtin_bit_cast(float, v); }
#define DPPH2(x, ctrl) u2h((unsigned)__builtin_amdgcn_update_dpp( \
    (int)h2u(x), (int)h2u(x), (ctrl), 0xF, 0xF, false))

#if defined(__has_builtin) && __has_builtin(__builtin_amdgcn_fdot2)
#define FDOT2(a, b, c) __builtin_amdgcn_fdot2((a), (b), (c), false)
#else
#define FDOT2(a, b, c) fmaf((float)(a).x, (float)(b).x, fmaf((float)(a).y, (float)(b).y, (c)))
#endif

// fuse out_proj+fc -> W3 (f32 + fp16-packed), pack fco weights to fp16.
__global__ __launch_bounds__(512) void fuse_proj_kernel(
    const float* __restrict__ fc_w, const float* __restrict__ fc_b,
    const float* __restrict__ op_w, const float* __restrict__ op_b,
    const float* __restrict__ fow,
    h2* __restrict__ w3h, float* __restrict__ w3f, float* __restrict__ b3,
    h2* __restrict__ fowh)
{
    __shared__ float lw[512];
    int t = threadIdx.x;           // 512 threads: o = t>>4 (0..31), j = t&15
    int o = t >> 4, j = t & 15;
    float acc = 0.f;
#pragma unroll
    for (int e = 0; e < 16; ++e)
        acc = fmaf(fc_w[o * 16 + e], op_w[e * 16 + j], acc);
    lw[t] = acc;
    if (j == 0) {
        float bb = fc_b[o];
#pragma unroll
        for (int e = 0; e < 16; ++e)
            bb = fmaf(fc_w[o * 16 + e], op_b[e], bb);
        b3[o] = bb;
    }
    // fco weight pack: 1024 floats -> 512 h2
    fowh[t] = __builtin_amdgcn_cvt_pkrtz(fow[2 * t], fow[2 * t + 1]);
    __syncthreads();
    if (t < 256) {
        float a = lw[2 * t], bv = lw[2 * t + 1];
        w3h[t] = __builtin_amdgcn_cvt_pkrtz(a, bv);
        w3f[2 * t] = a; w3f[2 * t + 1] = bv;
    }
}

// Per-node: gather nf -> fc1(relu) -> fc2 -> in_proj -> qkv, packed to fp16.
// Layout per node: 24 h2 = 96 B = 6 x dwordx4. q pre-scaled by 1/sqrt(8)*log2e.
__global__ __launch_bounds__(256) void node_qkv_kernel(
    const float* __restrict__ nf,
    const float* __restrict__ w1, const float* __restrict__ b1,
    const float* __restrict__ w2, const float* __restrict__ b2,
    const float* __restrict__ wip, const float* __restrict__ bip,
    float* __restrict__ qkvt, int N)
{
    int n = blockIdx.x * 256 + threadIdx.x;
    if (n >= N) return;
    const float2* nfp = reinterpret_cast<const float2*>(nf);
    float2 p0 = nfp[n * 3 + 0], p1 = nfp[n * 3 + 1], p2 = nfp[n * 3 + 2];
    float f[6] = {p0.x, p0.y, p1.x, p1.y, p2.x, p2.y};
    float h[32];
#pragma unroll
    for (int o = 0; o < 32; ++o) {
        float acc = b1[o];
#pragma unroll
        for (int i = 0; i < 6; ++i) acc = fmaf(f[i], w1[o * 6 + i], acc);
        h[o] = fmaxf(acc, 0.f);
    }
    float x[16];
#pragma unroll
    for (int e = 0; e < 16; ++e) {
        float acc = b2[e];
#pragma unroll
        for (int i = 0; i < 32; ++i) acc = fmaf(h[i], w2[e * 32 + i], acc);
        x[e] = acc;
    }
    float qkv[48];
#pragma unroll
    for (int c = 0; c < 48; ++c) {
        float acc = bip[c];
#pragma unroll
        for (int e = 0; e < 16; ++e) acc = fmaf(x[e], wip[c * 16 + e], acc);
        qkv[c] = acc;
    }
    const float cs = 0.35355339059327373f * 1.4426950408889634f; // 1/sqrt(8) * log2(e)
#pragma unroll
    for (int c = 0; c < 16; ++c) qkv[c] *= cs;
    h2 ph[24];
#pragma unroll
    for (int i = 0; i < 24; ++i)
        ph[i] = __builtin_amdgcn_cvt_pkrtz(qkv[2 * i], qkv[2 * i + 1]);
    f32x4* dst = reinterpret_cast<f32x4*>(qkvt) + (size_t)n * 6;
#pragma unroll
    for (int t = 0; t < 6; ++t) {
        f32x4 w;
        w.x = h2f(ph[4 * t + 0]); w.y = h2f(ph[4 * t + 1]);
        w.z = h2f(ph[4 * t + 2]); w.w = h2f(ph[4 * t + 3]);
        dst[t] = w;
    }
}

__global__ __launch_bounds__(256) void attn_tail_kernel(
    const int* __restrict__ s2l, const float* __restrict__ qkvt,
    const h2* __restrict__ w3h, const float* __restrict__ b3,
    const h2* __restrict__ fowh, const float* __restrict__ fob,
    float* __restrict__ out, int B)
{
    int tid = blockIdx.x * 256 + threadIdx.x;
    int b = tid >> 3;
    if (b >= B) return;
    int l = tid & 7;
    int idx = s2l[b * 8 + l];
    const f32x4* qp = reinterpret_cast<const f32x4*>(qkvt) + (size_t)idx * 6;
    f32x4 a0 = qp[0], a1 = qp[1], a2 = qp[2], a3 = qp[3], a4 = qp[4], a5 = qp[5];

    h2 qh[8] = {f2h(a0.x), f2h(a0.y), f2h(a0.z), f2h(a0.w),
                f2h(a1.x), f2h(a1.y), f2h(a1.z), f2h(a1.w)};
    h2 kh[8] = {f2h(a2.x), f2h(a2.y), f2h(a2.z), f2h(a2.w),
                f2h(a3.x), f2h(a3.y), f2h(a3.z), f2h(a3.w)};

    // half-mirrored copy (partner l^7); slots 4..6 are quad_perms of it
    h2 k7[8];
#pragma unroll
    for (int d = 0; d < 8; ++d) k7[d] = DPPH2(kh[d], 0x141);

    // scores: slot o = q(self) . k(lane^o); head0 = regs 0..3, head1 = 4..7
    float s0[8], s1[8];
#define SC_ID(slot, KS) { float x0 = 0.f, x1 = 0.f; \
    _Pragma("unroll") for (int d = 0; d < 4; ++d) { \
        x0 = FDOT2(qh[d], KS[d], x0); x1 = FDOT2(qh[4 + d], KS[4 + d], x1); } \
    s0[slot] = x0; s1[slot] = x1; }
#define SC_DPP(slot, KS, CTRL) { float x0 = 0.f, x1 = 0.f; \
    _Pragma("unroll") for (int d = 0; d < 4; ++d) { \
        x0 = FDOT2(qh[d], DPPH2(KS[d], CTRL), x0); \
        x1 = FDOT2(qh[4 + d], DPPH2(KS[4 + d], CTRL), x1); } \
    s0[slot] = x0; s1[slot] = x1; }
    SC_ID(0, kh)
    SC_DPP(1, kh, 0xB1)
    SC_DPP(2, kh, 0x4E)
    SC_DPP(3, kh, 0x1B)
    SC_DPP(4, k7, 0x1B)
    SC_DPP(5, k7, 0x4E)
    SC_DPP(6, k7, 0xB1)
    SC_ID(7, k7)
#undef SC_ID
#undef SC_DPP

    // softmax in exp2 domain (q pre-scaled by 1/sqrt(8)*log2e)
    float mx0 = fmaxf(fmaxf(fmaxf(s0[0], s0[1]), fmaxf(s0[2], s0[3])),
                      fmaxf(fmaxf(s0[4], s0[5]), fmaxf(s0[6], s0[7])));
    float mx1 = fmaxf(fmaxf(fmaxf(s1[0], s1[1]), fmaxf(s1[2], s1[3])),
                      fmaxf(fmaxf(s1[4], s1[5]), fmaxf(s1[6], s1[7])));
    float e0[8], e1[8];
    float sum0 = 0.f, sum1 = 0.f;
#pragma unroll
    for (int m = 0; m < 8; ++m) {
        e0[m] = exp2f(s0[m] - mx0); sum0 += e0[m];
        e1[m] = exp2f(s1[m] - mx1); sum1 += e1[m];
    }
    float r0 = __builtin_amdgcn_rcpf(sum0);
    float r1 = __builtin_amdgcn_rcpf(sum1);
#pragma unroll
    for (int m = 0; m < 8; ++m) { e0[m] *= r0; e1[m] *= r1; }

    // ctx: f32 accumulate via fma-mix (fp16 v source), same XOR-slot scheme
    h2 vh[8] = {f2h(a4.x), f2h(a4.y), f2h(a4.z), f2h(a4.w),
                f2h(a5.x), f2h(a5.y), f2h(a5.z), f2h(a5.w)};
    h2 v7[8];
#pragma unroll
    for (int d = 0; d < 8; ++d) v7[d] = DPPH2(vh[d], 0x141);

    float ctx[16];
#pragma unroll
    for (int c = 0; c < 16; ++c) ctx[c] = 0.f;
#define CTX_ID(slot, VS) { \
    _Pragma("unroll") for (int d = 0; d < 4; ++d) { \
        ctx[2*d]      = fmaf(e0[slot], (float)VS[d].x,     ctx[2*d]); \
        ctx[2*d+1]    = fmaf(e0[slot], (float)VS[d].y,     ctx[2*d+1]); \
        ctx[8+2*d]    = fmaf(e1[slot], (float)VS[4+d].x,   ctx[8+2*d]); \
        ctx[8+2*d+1]  = fmaf(e1[slot], (float)VS[4+d].y,   ctx[8+2*d+1]); } }
#define CTX_DPP(slot, VS, CTRL) { \
    _Pragma("unroll") for (int d = 0; d < 4; ++d) { \
        h2 t0v = DPPH2(VS[d], CTRL); h2 t1v = DPPH2(VS[4+d], CTRL); \
        ctx[2*d]      = fmaf(e0[slot], (float)t0v.x, ctx[2*d]); \
        ctx[2*d+1]    = fmaf(e0[slot], (float)t0v.y, ctx[2*d+1]); \
        ctx[8+2*d]    = fmaf(e1[slot], (float)t1v.x, ctx[8+2*d]); \
        ctx[8+2*d+1]  = fmaf(e1[slot], (float)t1v.y, ctx[8+2*d+1]); } }
    CTX_ID(0, vh)
    CTX_DPP(1, vh, 0xB1)
    CTX_DPP(2, vh, 0x4E)
    CTX_DPP(3, vh, 0x1B)
    CTX_DPP(4, v7, 0x1B)
    CTX_DPP(5, v7, 0x4E)
    CTX_DPP(6, v7, 0xB1)
    CTX_ID(7, v7)
#undef CTX_ID
#undef CTX_DPP

    // pack ctx -> fp16 pairs; fused out_proj+fc (16->32, relu) via fdot2
    h2 ch[8];
#pragma unroll
    for (int i = 0; i < 8; ++i)
        ch[i] = __builtin_amdgcn_cvt_pkrtz(ctx[2 * i], ctx[2 * i + 1]);
    h2 yh[16];
#pragma unroll
    for (int i = 0; i < 16; ++i) {
        float ya = b3[2 * i], yb = b3[2 * i + 1];
#pragma unroll
        for (int jj = 0; jj < 8; ++jj) {
            ya = FDOT2(ch[jj], w3h[(2 * i) * 8 + jj], ya);
            yb = FDOT2(ch[jj], w3h[(2 * i + 1) * 8 + jj], yb);
        }
        yh[i] = __builtin_amdgcn_cvt_pkrtz(fmaxf(ya, 0.f), fmaxf(yb, 0.f));
    }

    // mean over 8 tokens: DPP butterfly on packed fp16 (xor1, xor2, xor4)
#pragma unroll
    for (int i = 0; i < 16; ++i) {
        yh[i] = yh[i] + DPPH2(yh[i], 0xB1);
        yh[i] = yh[i] + DPPH2(yh[i], 0x4E);
        h2 t = DPPH2(yh[i], 0x141);   // xor7
        t = DPPH2(t, 0x1B);           // xor3 of that = xor4
        yh[i] = yh[i] + t;
    }

    // fco: each of the 8 lanes computes 4 outputs via fdot2 on packed sums
    float o4[4];
#pragma unroll
    for (int j = 0; j < 4; ++j) {
        int oo = l * 4 + j;
        float acc = 0.f;
#pragma unroll
        for (int i = 0; i < 16; ++i)
            acc = FDOT2(yh[i], fowh[oo * 16 + i], acc);
        o4[j] = fmaf(acc, 0.125f, fob[oo]);  // fold mean's 1/8
    }
    f32x4 res; res.x = o4[0]; res.y = o4[1]; res.z = o4[2]; res.w = o4[3];
    __builtin_nontemporal_store(res, reinterpret_cast<f32x4*>(out) + (b * 8 + l));
}

// ---------------- fallback: round-1 monolithic kernel (if ws too small) ----------------
__global__ __launch_bounds__(256) void loop_embed_kernel(
    const float* __restrict__ nf, const int* __restrict__ s2l,
    const float* __restrict__ w1, const float* __restrict__ b1,
    const float* __restrict__ w2, const float* __restrict__ b2,
    const float* __restrict__ wip, const float* __restrict__ bip,
    const float* __restrict__ w3, const float* __restrict__ b3,
    const float* __restrict__ fow, const float* __restrict__ fob,
    float* __restrict__ out, int B)
{
    int tid = blockIdx.x * 256 + threadIdx.x;
    int b = tid >> 3;
    if (b >= B) return;
    int l = tid & 7;
    int idx = s2l[b * 8 + l];
    const float2* nfp = reinterpret_cast<const float2*>(nf);
    float2 p0 = nfp[idx * 3 + 0], p1 = nfp[idx * 3 + 1], p2 = nfp[idx * 3 + 2];
    float f[6] = {p0.x, p0.y, p1.x, p1.y, p2.x, p2.y};
    float h[32];
#pragma unroll
    for (int o = 0; o < 32; ++o) {
        float acc = b1[o];
#pragma unroll
        for (int i = 0; i < 6; ++i) acc = fmaf(f[i], w1[o * 6 + i], acc);
        h[o] = fmaxf(acc, 0.f);
    }
    float x[16];
#pragma unroll
    for (int e = 0; e < 16; ++e) {
        float acc = b2[e];
#pragma unroll
        for (int i = 0; i < 32; ++i) acc = fmaf(h[i], w2[e * 32 + i], acc);
        x[e] = acc;
    }
    float q[16], k[16], v[16];
#pragma unroll
    for (int c = 0; c < 16; ++c) {
        float aq = bip[c], ak = bip[16 + c], av = bip[32 + c];
#pragma unroll
        for (int e = 0; e < 16; ++e) {
            aq = fmaf(x[e], wip[c * 16 + e], aq);
            ak = fmaf(x[e], wip[(16 + c) * 16 + e], ak);
            av = fmaf(x[e], wip[(32 + c) * 16 + e], av);
        }
        q[c] = aq; k[c] = ak; v[c] = av;
    }
    int lane = threadIdx.x & 63;
    int gb = lane & 56;
    float s0[8], s1[8];
#pragma unroll
    for (int m = 0; m < 8; ++m) {
        float a0 = 0.f, a1 = 0.f;
#pragma unroll
        for (int d = 0; d < 8; ++d) {
            a0 = fmaf(q[d], __shfl(k[d], gb + m, 64), a0);
            a1 = fmaf(q[8 + d], __shfl(k[8 + d], gb + m, 64), a1);
        }
        s0[m] = a0; s1[m] = a1;
    }
    const float sc = 0.35355339059327373f;
    float mx0 = s0[0], mx1 = s1[0];
#pragma unroll
    for (int m = 1; m < 8; ++m) { mx0 = fmaxf(mx0, s0[m]); mx1 = fmaxf(mx1, s1[m]); }
    float e0[8], e1[8];
    float sum0 = 0.f, sum1 = 0.f;
#pragma unroll
    for (int m = 0; m < 8; ++m) {
        e0[m] = __expf((s0[m] - mx0) * sc); sum0 += e0[m];
        e1[m] = __expf((s1[m] - mx1) * sc); sum1 += e1[m];
    }
    float r0 = 1.0f / sum0, r1 = 1.0f / sum1;
    float ctx[16];
#pragma unroll
    for (int c = 0; c < 16; ++c) ctx[c] = 0.f;
#pragma unroll
    for (int m = 0; m < 8; ++m) {
#pragma unroll
        for (int c = 0; c < 8; ++c)
            ctx[c] = fmaf(e0[m], __shfl(v[c], gb + m, 64), ctx[c]);
#pragma unroll
        for (int c = 8; c < 16; ++c)
            ctx[c] = fmaf(e1[m], __shfl(v[c], gb + m, 64), ctx[c]);
    }
#pragma unroll
    for (int c = 0; c < 8; ++c)  ctx[c] *= r0;
#pragma unroll
    for (int c = 8; c < 16; ++c) ctx[c] *= r1;
    float y[32];
#pragma unroll
    for (int o = 0; o < 32; ++o) {
        float acc = b3[o];
#pragma unroll
        for (int j = 0; j < 16; ++j) acc = fmaf(ctx[j], w3[o * 16 + j], acc);
        y[o] = fmaxf(acc, 0.f);
    }
#pragma unroll
    for (int o = 0; o < 32; ++o) {
        y[o] += __shfl_xor(y[o], 1, 64);
        y[o] += __shfl_xor(y[o], 2, 64);
        y[o] += __shfl_xor(y[o], 4, 64);
    }
    float o4[4];
#pragma unroll
    for (int j = 0; j < 4; ++j) {
        int oo = l * 4 + j;
        float acc = 0.f;
#pragma unroll
        for (int i = 0; i < 32; ++i) acc = fmaf(y[i], fow[oo * 32 + i], acc);
        o4[j] = fmaf(acc, 0.125f, fob[oo]);
    }
    reinterpret_cast<float4*>(out)[b * 8 + l] = make_float4(o4[0], o4[1], o4[2], o4[3]);
}

extern "C" void kernel_launch(void* const* d_in, const int* in_sizes, int n_in,
                              void* d_out, int out_size, void* d_ws, size_t ws_size,
                              hipStream_t stream) {
    const float* nf  = (const float*)d_in[0];
    const int*   s2l = (const int*)d_in[1];
    const float* w1  = (const float*)d_in[2];
    const float* b1  = (const float*)d_in[3];
    const float* w2  = (const float*)d_in[4];
    const float* b2  = (const float*)d_in[5];
    const float* wip = (const float*)d_in[6];
    const float* bip = (const float*)d_in[7];
    const float* opw = (const float*)d_in[8];
    const float* opb = (const float*)d_in[9];
    const float* fcw = (const float*)d_in[10];
    const float* fcb = (const float*)d_in[11];
    const float* fow = (const float*)d_in[12];
    const float* fob = (const float*)d_in[13];
    float* out = (float*)d_out;

    int N = in_sizes[0] / 6;
    int B = in_sizes[1] / 8;

    // ws layout (dwords): [0,256) w3h  [256,768) fowh  [768,800) b3
    //                     [800,1312) w3f (fallback)  [1312,...) fp16 qkv table
    unsigned* wsd = (unsigned*)d_ws;
    h2*    w3h  = (h2*)(wsd);
    h2*    fowh = (h2*)(wsd + 256);
    float* b3   = (float*)(wsd + 768);
    float* w3f  = (float*)(wsd + 800);
    float* qkvt = (float*)(wsd + 1312);   // 16B-aligned (1312*4 = 5248)

    size_t need = (size_t)(1312 + (size_t)N * 12) * 4;   // 12 dwords = 96 B/node

    fuse_proj_kernel<<<1, 512, 0, stream>>>(fcw, fcb, opw, opb, fow,
                                            w3h, w3f, b3, fowh);

    int total = B * 8;
    int blocks = (total + 255) / 256;

    if (ws_size >= need) {
        node_qkv_kernel<<<(N + 255) / 256, 256, 0, stream>>>(
            nf, w1, b1, w2, b2, wip, bip, qkvt, N);
        attn_tail_kernel<<<blocks, 256, 0, stream>>>(
            s2l, qkvt, w3h, b3, fowh, fob, out, B);
    } else {
        loop_embed_kernel<<<blocks, 256, 0, stream>>>(
            nf, s2l, w1, b1, w2, b2, wip, bip, w3f, b3, fow, fob, out, B);
    }
    (void)n_in; (void)out_size;
}